// Round 1
// baseline (1671.041 us; speedup 1.0000x reference)
//
#include <hip/hip_runtime.h>
#include <cstddef>

// ---------------------------------------------------------------------------
// AFNO: rfft2(32x32, ortho) -> block-diag complex 2-layer MLP -> irfft2
// B=64, H=W=32, C=768, NUM_BLOCKS=4, BLOCK=192, Wf=17
// ---------------------------------------------------------------------------

namespace {

constexpr int BATCH = 64;
constexpr int Hh    = 32;
constexpr int Ww    = 32;
constexpr int WF    = 17;   // 32/2 + 1
constexpr int CC    = 768;
constexpr int BLK   = 192;

// twiddles: C32[j] = cos(2*pi*j/32), S32[j] = sin(2*pi*j/32)
constexpr float C32[32] = {
   1.0000000000f,  0.9807852804f,  0.9238795325f,  0.8314696123f,
   0.7071067812f,  0.5555702330f,  0.3826834324f,  0.1950903220f,
   0.0000000000f, -0.1950903220f, -0.3826834324f, -0.5555702330f,
  -0.7071067812f, -0.8314696123f, -0.9238795325f, -0.9807852804f,
  -1.0000000000f, -0.9807852804f, -0.9238795325f, -0.8314696123f,
  -0.7071067812f, -0.5555702330f, -0.3826834324f, -0.1950903220f,
   0.0000000000f,  0.1950903220f,  0.3826834324f,  0.5555702330f,
   0.7071067812f,  0.8314696123f,  0.9238795325f,  0.9807852804f
};
constexpr float S32[32] = {
   0.0000000000f,  0.1950903220f,  0.3826834324f,  0.5555702330f,
   0.7071067812f,  0.8314696123f,  0.9238795325f,  0.9807852804f,
   1.0000000000f,  0.9807852804f,  0.9238795325f,  0.8314696123f,
   0.7071067812f,  0.5555702330f,  0.3826834324f,  0.1950903220f,
   0.0000000000f, -0.1950903220f, -0.3826834324f, -0.5555702330f,
  -0.7071067812f, -0.8314696123f, -0.9238795325f, -0.9807852804f,
  -1.0000000000f, -0.9807852804f, -0.9238795325f, -0.8314696123f,
  -0.7071067812f, -0.5555702330f, -0.3826834324f, -0.1950903220f
};

} // namespace

// ---------------------------------------------------------------------------
// Stage 1: real FFT along W.  x[bh][w][c] (w stride = CC) -> Xr/Xi[bh][k][c]
// grid: nBH*3 blocks, 256 threads; thread = (bh, c)
// ---------------------------------------------------------------------------
__global__ __launch_bounds__(256) void k_rfft_w(const float* __restrict__ x,
                                                float* __restrict__ Xr,
                                                float* __restrict__ Xi) {
    const int bid = blockIdx.x;
    const int bh  = bid / 3;
    const int c   = (bid % 3) * 256 + threadIdx.x;

    const float* px = x + (size_t)bh * Ww * CC + c;
    float v[32];
#pragma unroll
    for (int w = 0; w < 32; ++w) v[w] = px[(size_t)w * CC];

    const size_t obase = (size_t)bh * WF * CC + c;
#pragma unroll
    for (int k = 0; k <= 16; ++k) {
        float sr = 0.f, si = 0.f;
#pragma unroll
        for (int w = 0; w < 32; ++w) {
            const int t = (k * w) & 31;
            sr = fmaf(v[w],  C32[t], sr);
            si = fmaf(v[w], -S32[t], si);
        }
        Xr[obase + (size_t)k * CC] = sr;
        Xi[obase + (size_t)k * CC] = si;
    }
}

// ---------------------------------------------------------------------------
// Stage 2/4: complex FFT along H (in place).  INV=false: e^{-i}, scale 1/32.
// INV=true: e^{+i}, no scale.  grid: nB*WF*3, thread = (b, kw, c)
// ---------------------------------------------------------------------------
template <bool INV>
__global__ __launch_bounds__(256) void k_fft_h(float* __restrict__ Xr,
                                               float* __restrict__ Xi) {
    const int bid = blockIdx.x;
    const int b   = bid / (WF * 3);
    const int rem = bid % (WF * 3);
    const int kw  = rem / 3;
    const int c   = (rem % 3) * 256 + threadIdx.x;

    const size_t sh   = (size_t)WF * CC;
    const size_t base = ((size_t)b * Hh * WF + kw) * CC + c;

    float ar[32], ai[32];
#pragma unroll
    for (int h = 0; h < 32; ++h) {
        ar[h] = Xr[base + (size_t)h * sh];
        ai[h] = Xi[base + (size_t)h * sh];
    }
#pragma unroll
    for (int kh = 0; kh < 32; ++kh) {
        float cr = 0.f, ci = 0.f;
#pragma unroll
        for (int h = 0; h < 32; ++h) {
            const int t = (kh * h) & 31;
            if (INV) {
                cr = fmaf(ar[h], C32[t], fmaf(-ai[h], S32[t], cr));
                ci = fmaf(ar[h], S32[t], fmaf( ai[h], C32[t], ci));
            } else {
                cr = fmaf(ar[h], C32[t], fmaf( ai[h], S32[t], cr));
                ci = fmaf(ai[h], C32[t], fmaf(-ar[h], S32[t], ci));
            }
        }
        const float s = INV ? 1.0f : 0.03125f;
        Xr[base + (size_t)kh * sh] = cr * s;
        Xi[base + (size_t)kh * sh] = ci * s;
    }
}

// ---------------------------------------------------------------------------
// Stage 3: block-diagonal complex 2-layer MLP, per frequency point (in place).
// WG = 16 points x 1 block(192 ch).  256 threads: k = (tid&63)+64j (j<3),
// points = (tid>>6)*4 .. +3.   LDS pad 20 to break bank conflicts.
// ---------------------------------------------------------------------------
__device__ __forceinline__ void ld4(const float* p, float v[4]) {
    const float4 t = *reinterpret_cast<const float4*>(p);
    v[0] = t.x; v[1] = t.y; v[2] = t.z; v[3] = t.w;
}

__global__ __launch_bounds__(256) void k_mix(float* __restrict__ Xr,
                                             float* __restrict__ Xi,
                                             const float* __restrict__ w1,
                                             const float* __restrict__ b1,
                                             const float* __restrict__ w2,
                                             const float* __restrict__ b2) {
    __shared__ float sAr[BLK][20];
    __shared__ float sAi[BLK][20];
    __shared__ float sBr[BLK][20];
    __shared__ float sBi[BLK][20];

    const int blk = blockIdx.x & 3;
    const int pt0 = (blockIdx.x >> 2) * 16;
    const int tid = threadIdx.x;

    // ---- load x tile: 16 points x 192 ch (r & i), coalesced float4 ----
#pragma unroll
    for (int i = 0; i < 3; ++i) {
        const int idx = tid + 256 * i;      // 0..767 float4 slots
        const int p   = idx / 48;
        const int d4  = (idx % 48) * 4;
        const size_t g = (size_t)(pt0 + p) * CC + blk * BLK + d4;
        const float4 vr = *reinterpret_cast<const float4*>(Xr + g);
        const float4 vi = *reinterpret_cast<const float4*>(Xi + g);
        sAr[d4 + 0][p] = vr.x; sAr[d4 + 1][p] = vr.y;
        sAr[d4 + 2][p] = vr.z; sAr[d4 + 3][p] = vr.w;
        sAi[d4 + 0][p] = vi.x; sAi[d4 + 1][p] = vi.y;
        sAi[d4 + 2][p] = vi.z; sAi[d4 + 3][p] = vi.w;
    }
    __syncthreads();

    const int lk = tid & 63;
    const int pg = (tid >> 6) * 4;

    const float* W1r = w1 + (size_t)(0 * 4 + blk) * BLK * BLK;
    const float* W1i = w1 + (size_t)(1 * 4 + blk) * BLK * BLK;
    const float* W2r = w2 + (size_t)(0 * 4 + blk) * BLK * BLK;
    const float* W2i = w2 + (size_t)(1 * 4 + blk) * BLK * BLK;

    // ---- S1: r1 = relu(xr W1r - xi W1i + b1r); i1 = relu(xr W1i + xi W1r + b1i)
    float a1r[3][4] = {}, a1i[3][4] = {};
    for (int d = 0; d < BLK; ++d) {
        float wr[3], wi[3];
#pragma unroll
        for (int j = 0; j < 3; ++j) {
            wr[j] = W1r[d * BLK + lk + 64 * j];
            wi[j] = W1i[d * BLK + lk + 64 * j];
        }
        float xr[4], xi[4];
        ld4(&sAr[d][pg], xr);
        ld4(&sAi[d][pg], xi);
#pragma unroll
        for (int j = 0; j < 3; ++j)
#pragma unroll
            for (int p = 0; p < 4; ++p) {
                a1r[j][p] = fmaf(xr[p], wr[j], fmaf(-xi[p], wi[j], a1r[j][p]));
                a1i[j][p] = fmaf(xr[p], wi[j], fmaf( xi[p], wr[j], a1i[j][p]));
            }
    }
#pragma unroll
    for (int j = 0; j < 3; ++j) {
        const float br = b1[(size_t)(0 * 4 + blk) * BLK + lk + 64 * j];
        const float bi = b1[(size_t)(1 * 4 + blk) * BLK + lk + 64 * j];
#pragma unroll
        for (int p = 0; p < 4; ++p) {
            float rv = a1r[j][p] + br; rv = rv > 0.f ? rv : 0.f;
            float iv = a1i[j][p] + bi; iv = iv > 0.f ? iv : 0.f;
            sBr[lk + 64 * j][pg + p] = rv;
            sBi[lk + 64 * j][pg + p] = iv;
        }
    }
    __syncthreads();

    // ---- S2: r2 = r1 W2r - i1 W2i + b2r
    float a2r[3][4] = {};
    for (int d = 0; d < BLK; ++d) {
        float wr[3], wi[3];
#pragma unroll
        for (int j = 0; j < 3; ++j) {
            wr[j] = W2r[d * BLK + lk + 64 * j];
            wi[j] = W2i[d * BLK + lk + 64 * j];
        }
        float rr[4], ii[4];
        ld4(&sBr[d][pg], rr);
        ld4(&sBi[d][pg], ii);
#pragma unroll
        for (int j = 0; j < 3; ++j)
#pragma unroll
            for (int p = 0; p < 4; ++p)
                a2r[j][p] = fmaf(rr[p], wr[j], fmaf(-ii[p], wi[j], a2r[j][p]));
    }
#pragma unroll
    for (int j = 0; j < 3; ++j) {
        const float br = b2[(size_t)(0 * 4 + blk) * BLK + lk + 64 * j];
#pragma unroll
        for (int p = 0; p < 4; ++p) a2r[j][p] += br;
    }
    // stash r2 in sAr (x no longer needed)
#pragma unroll
    for (int j = 0; j < 3; ++j)
#pragma unroll
        for (int p = 0; p < 4; ++p)
            sAr[lk + 64 * j][pg + p] = a2r[j][p];
    __syncthreads();

    // ---- S3: i2 = r2 W2i + i1 W2r + b2i   (uses UPDATED r2, per reference)
    float a2i[3][4] = {};
    for (int d = 0; d < BLK; ++d) {
        float wr[3], wi[3];
#pragma unroll
        for (int j = 0; j < 3; ++j) {
            wr[j] = W2r[d * BLK + lk + 64 * j];
            wi[j] = W2i[d * BLK + lk + 64 * j];
        }
        float rr[4], ii[4];
        ld4(&sAr[d][pg], rr);   // r2
        ld4(&sBi[d][pg], ii);   // i1
#pragma unroll
        for (int j = 0; j < 3; ++j)
#pragma unroll
            for (int p = 0; p < 4; ++p)
                a2i[j][p] = fmaf(rr[p], wi[j], fmaf(ii[p], wr[j], a2i[j][p]));
    }
#pragma unroll
    for (int j = 0; j < 3; ++j) {
        const float bi = b2[(size_t)(1 * 4 + blk) * BLK + lk + 64 * j];
#pragma unroll
        for (int p = 0; p < 4; ++p) a2i[j][p] += bi;
    }

    // ---- write back (in place; this WG owns these (point, block) slots) ----
#pragma unroll
    for (int j = 0; j < 3; ++j)
#pragma unroll
        for (int p = 0; p < 4; ++p) {
            const size_t g = (size_t)(pt0 + pg + p) * CC + blk * BLK + lk + 64 * j;
            Xr[g] = a2r[j][p];
            Xi[g] = a2i[j][p];
        }
}

// ---------------------------------------------------------------------------
// Stage 5: inverse real FFT along W.  out[w] = (Xr0 + (-1)^w Xr16
//            + 2*sum_{k=1..15}(Xr_k cos - Xi_k sin)) / 32
// (imag of bins 0 and 16 ignored — pocketfft c2r semantics)
// ---------------------------------------------------------------------------
__global__ __launch_bounds__(256) void k_irfft_w(const float* __restrict__ Xr,
                                                 const float* __restrict__ Xi,
                                                 float* __restrict__ out) {
    const int bid = blockIdx.x;
    const int bh  = bid / 3;
    const int c   = (bid % 3) * 256 + threadIdx.x;

    const size_t ibase = (size_t)bh * WF * CC + c;
    float xr[17], xi[17];
#pragma unroll
    for (int k = 0; k < 17; ++k) {
        xr[k] = Xr[ibase + (size_t)k * CC];
        xi[k] = Xi[ibase + (size_t)k * CC];
    }
    float* po = out + (size_t)bh * Ww * CC + c;
#pragma unroll
    for (int w = 0; w < 32; ++w) {
        float s = xr[0] + ((w & 1) ? -xr[16] : xr[16]);
#pragma unroll
        for (int k = 1; k <= 15; ++k) {
            const int t = (k * w) & 31;
            s = fmaf(2.f * xr[k],  C32[t], s);
            s = fmaf(2.f * xi[k], -S32[t], s);
        }
        po[(size_t)w * CC] = s * 0.03125f;
    }
}

// ---------------------------------------------------------------------------
extern "C" void kernel_launch(void* const* d_in, const int* in_sizes, int n_in,
                              void* d_out, int out_size, void* d_ws, size_t ws_size,
                              hipStream_t stream) {
    const float* x  = (const float*)d_in[0];
    const float* w1 = (const float*)d_in[1];
    const float* b1 = (const float*)d_in[2];
    const float* w2 = (const float*)d_in[3];
    const float* b2 = (const float*)d_in[4];
    float* out = (float*)d_out;

    // choose largest batch chunk whose Xr+Xi (fp32) fits in workspace
    int chunkB = BATCH;
    while (chunkB > 1 &&
           (size_t)2 * chunkB * Hh * WF * CC * sizeof(float) > ws_size)
        chunkB >>= 1;

    float* Xr = (float*)d_ws;
    float* Xi = Xr + (size_t)chunkB * Hh * WF * CC;

    for (int b0 = 0; b0 < BATCH; b0 += chunkB) {
        const float* xc = x   + (size_t)b0 * (Hh * Ww) * CC;
        float*       oc = out + (size_t)b0 * (Hh * Ww) * CC;

        k_rfft_w<<<dim3(chunkB * Hh * 3), dim3(256), 0, stream>>>(xc, Xr, Xi);
        k_fft_h<false><<<dim3(chunkB * WF * 3), dim3(256), 0, stream>>>(Xr, Xi);
        // points = chunkB*32*17 = chunkB*544; 16-point tiles * 4 blocks
        k_mix<<<dim3(chunkB * 136), dim3(256), 0, stream>>>(Xr, Xi, w1, b1, w2, b2);
        k_fft_h<true><<<dim3(chunkB * WF * 3), dim3(256), 0, stream>>>(Xr, Xi);
        k_irfft_w<<<dim3(chunkB * Hh * 3), dim3(256), 0, stream>>>(Xr, Xi, oc);
    }
}

// Round 2
// 552.806 us; speedup vs baseline: 3.0228x; 3.0228x over previous
//
#include <hip/hip_runtime.h>
#include <cstddef>
#include <cstdint>

// ---------------------------------------------------------------------------
// AFNO: rfft2(32x32, ortho) -> block-diag complex 2-layer MLP -> irfft2
// B=64, H=W=32, C=768, NUM_BLOCKS=4, BLOCK=192, Wf=17
// Round 2: mix on MFMA (bf16 in, fp32 acc). FFT stages unchanged.
// ---------------------------------------------------------------------------

typedef __attribute__((ext_vector_type(8))) short bf16x8;
typedef __attribute__((ext_vector_type(4))) float f32x4;

namespace {

constexpr int BATCH = 64;
constexpr int Hh    = 32;
constexpr int Ww    = 32;
constexpr int WF    = 17;   // 32/2 + 1
constexpr int CC    = 768;
constexpr int BLK   = 192;
constexpr int PTS_PER_B = Hh * WF;            // 544 frequency points per batch
constexpr size_t PW_ELEMS = 16u * 36864u;     // 16 packed 192x192 bf16 matrices
constexpr size_t PW_BYTES = PW_ELEMS * 2u;    // 1,179,648 B (16B aligned)

// twiddles: C32[j] = cos(2*pi*j/32), S32[j] = sin(2*pi*j/32)
constexpr float C32[32] = {
   1.0000000000f,  0.9807852804f,  0.9238795325f,  0.8314696123f,
   0.7071067812f,  0.5555702330f,  0.3826834324f,  0.1950903220f,
   0.0000000000f, -0.1950903220f, -0.3826834324f, -0.5555702330f,
  -0.7071067812f, -0.8314696123f, -0.9238795325f, -0.9807852804f,
  -1.0000000000f, -0.9807852804f, -0.9238795325f, -0.8314696123f,
  -0.7071067812f, -0.5555702330f, -0.3826834324f, -0.1950903220f,
   0.0000000000f,  0.1950903220f,  0.3826834324f,  0.5555702330f,
   0.7071067812f,  0.8314696123f,  0.9238795325f,  0.9807852804f
};
constexpr float S32[32] = {
   0.0000000000f,  0.1950903220f,  0.3826834324f,  0.5555702330f,
   0.7071067812f,  0.8314696123f,  0.9238795325f,  0.9807852804f,
   1.0000000000f,  0.9807852804f,  0.9238795325f,  0.8314696123f,
   0.7071067812f,  0.5555702330f,  0.3826834324f,  0.1950903220f,
   0.0000000000f, -0.1950903220f, -0.3826834324f, -0.5555702330f,
  -0.7071067812f, -0.8314696123f, -0.9238795325f, -0.9807852804f,
  -1.0000000000f, -0.9807852804f, -0.9238795325f, -0.8314696123f,
  -0.7071067812f, -0.5555702330f, -0.3826834324f, -0.1950903220f
};

} // namespace

__device__ __forceinline__ ushort f2bf(float f) {
    union { float f; unsigned u; } v; v.f = f;
    const unsigned r = (v.u + 0x7FFFu + ((v.u >> 16) & 1u)) >> 16;
    return (ushort)r;
}

__device__ __forceinline__ bf16x8 neg8(bf16x8 a) {
    union { bf16x8 v; uint4 u; } t; t.v = a;
    t.u.x ^= 0x80008000u; t.u.y ^= 0x80008000u;
    t.u.z ^= 0x80008000u; t.u.w ^= 0x80008000u;
    return t.v;
}

// ---------------------------------------------------------------------------
// Weight pre-pack: 16 matrices (W1r,W1i,W2r,W2i) x 4 blk, each 192x192 fp32
// (row = reduce dim d, col = out k) -> bf16 MFMA B-fragment order:
// pw[mi][kk][nf][lane][i]  with  d = kk*32 + (lane>>4)*8 + i, col = nf*16 + (lane&15)
// ---------------------------------------------------------------------------
__global__ __launch_bounds__(256) void k_pack(const float* __restrict__ w1,
                                              const float* __restrict__ w2,
                                              ushort* __restrict__ pw) {
    const unsigned idx = blockIdx.x * 256u + threadIdx.x;   // 0 .. 589823
    const unsigned mi = idx / 36864u;       // which*4 + blk
    const unsigned r  = idx % 36864u;
    const unsigned kk = r / 6144u;
    const unsigned r2 = r % 6144u;
    const unsigned nf = r2 / 512u;
    const unsigned r3 = r2 % 512u;
    const unsigned lane = r3 / 8u;
    const unsigned i  = r3 % 8u;

    const unsigned d   = kk * 32u + (lane >> 4) * 8u + i;
    const unsigned col = nf * 16u + (lane & 15u);
    const unsigned which = mi >> 2, blk = mi & 3u;

    const float* src = (which < 2u)
        ? (w1 + (size_t)(which * 4u + blk) * BLK * BLK)
        : (w2 + (size_t)((which - 2u) * 4u + blk) * BLK * BLK);
    pw[idx] = f2bf(src[(size_t)d * BLK + col]);
}

// ---------------------------------------------------------------------------
// Stage 1: real FFT along W.  x[bh][w][c] -> Xr/Xi[bh][k][c]
// ---------------------------------------------------------------------------
__global__ __launch_bounds__(256) void k_rfft_w(const float* __restrict__ x,
                                                float* __restrict__ Xr,
                                                float* __restrict__ Xi) {
    const int bid = blockIdx.x;
    const int bh  = bid / 3;
    const int c   = (bid % 3) * 256 + threadIdx.x;

    const float* px = x + (size_t)bh * Ww * CC + c;
    float v[32];
#pragma unroll
    for (int w = 0; w < 32; ++w) v[w] = px[(size_t)w * CC];

    const size_t obase = (size_t)bh * WF * CC + c;
#pragma unroll
    for (int k = 0; k <= 16; ++k) {
        float sr = 0.f, si = 0.f;
#pragma unroll
        for (int w = 0; w < 32; ++w) {
            const int t = (k * w) & 31;
            sr = fmaf(v[w],  C32[t], sr);
            si = fmaf(v[w], -S32[t], si);
        }
        Xr[obase + (size_t)k * CC] = sr;
        Xi[obase + (size_t)k * CC] = si;
    }
}

// ---------------------------------------------------------------------------
// Stage 2/4: complex FFT along H (in place).
// ---------------------------------------------------------------------------
template <bool INV>
__global__ __launch_bounds__(256) void k_fft_h(float* __restrict__ Xr,
                                               float* __restrict__ Xi) {
    const int bid = blockIdx.x;
    const int b   = bid / (WF * 3);
    const int rem = bid % (WF * 3);
    const int kw  = rem / 3;
    const int c   = (rem % 3) * 256 + threadIdx.x;

    const size_t sh   = (size_t)WF * CC;
    const size_t base = ((size_t)b * Hh * WF + kw) * CC + c;

    float ar[32], ai[32];
#pragma unroll
    for (int h = 0; h < 32; ++h) {
        ar[h] = Xr[base + (size_t)h * sh];
        ai[h] = Xi[base + (size_t)h * sh];
    }
#pragma unroll
    for (int kh = 0; kh < 32; ++kh) {
        float cr = 0.f, ci = 0.f;
#pragma unroll
        for (int h = 0; h < 32; ++h) {
            const int t = (kh * h) & 31;
            if (INV) {
                cr = fmaf(ar[h], C32[t], fmaf(-ai[h], S32[t], cr));
                ci = fmaf(ar[h], S32[t], fmaf( ai[h], C32[t], ci));
            } else {
                cr = fmaf(ar[h], C32[t], fmaf( ai[h], S32[t], cr));
                ci = fmaf(ai[h], C32[t], fmaf(-ar[h], S32[t], ci));
            }
        }
        const float s = INV ? 1.0f : 0.03125f;
        Xr[base + (size_t)kh * sh] = cr * s;
        Xi[base + (size_t)kh * sh] = ci * s;
    }
}

// ---------------------------------------------------------------------------
// Stage 3: MFMA mix. One WG = 64 points x 1 block (192 ch).
// 4 waves, each M=64 x N=48 (4 m-frags x 3 n-frags of 16x16x32 MFMA).
// LDS: x / r1,i1 / r2 staged as bf16, row stride 200 ushorts (400B).
// S1: r1=relu(xr W1r - xi W1i + b1r), i1=relu(xr W1i + xi W1r + b1i)
// S2: r2 = r1 W2r - i1 W2i + b2r
// S3: i2 = r2 W2i + i1 W2r + b2i   (uses UPDATED r2, per reference)
// ---------------------------------------------------------------------------
__global__ __launch_bounds__(256) void k_mix_mfma(
        float* __restrict__ Xr, float* __restrict__ Xi,
        const ushort* __restrict__ pw,
        const float* __restrict__ b1, const float* __restrict__ b2,
        int P) {

    __shared__ ushort bufR[64][200];
    __shared__ ushort bufI[64][200];

    const int blk = blockIdx.x & 3;
    const int pt0 = (blockIdx.x >> 2) * 64;
    const int tid = threadIdx.x;

    // ---- cooperative x-tile load: fp32 global -> bf16 LDS ----
#pragma unroll
    for (int j = 0; j < 12; ++j) {
        const int flat = j * 256 + tid;       // float4 slot, 0..3071
        const int row  = flat / 48;
        const int c4   = flat % 48;
        const int point = pt0 + row;
        float4 vr = make_float4(0.f, 0.f, 0.f, 0.f), vi = vr;
        if (point < P) {
            const size_t g = (size_t)point * CC + blk * BLK + c4 * 4;
            vr = *(const float4*)(Xr + g);
            vi = *(const float4*)(Xi + g);
        }
        ushort* dr = &bufR[row][c4 * 4];
        dr[0] = f2bf(vr.x); dr[1] = f2bf(vr.y); dr[2] = f2bf(vr.z); dr[3] = f2bf(vr.w);
        ushort* di = &bufI[row][c4 * 4];
        di[0] = f2bf(vi.x); di[1] = f2bf(vi.y); di[2] = f2bf(vi.z); di[3] = f2bf(vi.w);
    }
    __syncthreads();

    const int wv = tid >> 6;
    const int l  = tid & 63;
    const int lc = l & 15;
    const int lg = l >> 4;
    const int col0 = wv * 48;

    const ushort* pW1r = pw + (size_t)(0 * 4 + blk) * 36864;
    const ushort* pW1i = pw + (size_t)(1 * 4 + blk) * 36864;
    const ushort* pW2r = pw + (size_t)(2 * 4 + blk) * 36864;
    const ushort* pW2i = pw + (size_t)(3 * 4 + blk) * 36864;

    // ================= S1 =================
    f32x4 accR[4][3], accI[4][3];
#pragma unroll
    for (int n = 0; n < 3; ++n) {
        const float br = b1[(size_t)(0 * 4 + blk) * BLK + col0 + n * 16 + lc];
        const float bi = b1[(size_t)(1 * 4 + blk) * BLK + col0 + n * 16 + lc];
#pragma unroll
        for (int m = 0; m < 4; ++m) {
            accR[m][n] = (f32x4){br, br, br, br};
            accI[m][n] = (f32x4){bi, bi, bi, bi};
        }
    }

    for (int kk = 0; kk < 6; ++kk) {
        bf16x8 ar[4], ai[4], ain[4];
#pragma unroll
        for (int m = 0; m < 4; ++m) {
            ar[m]  = *(const bf16x8*)&bufR[m * 16 + lc][kk * 32 + lg * 8];
            ai[m]  = *(const bf16x8*)&bufI[m * 16 + lc][kk * 32 + lg * 8];
            ain[m] = neg8(ai[m]);
        }
        bf16x8 wr[3], wi[3];
#pragma unroll
        for (int n = 0; n < 3; ++n) {
            const size_t off = ((size_t)(kk * 12 + wv * 3 + n) * 64 + l) * 8;
            wr[n] = *(const bf16x8*)(pW1r + off);
            wi[n] = *(const bf16x8*)(pW1i + off);
        }
#pragma unroll
        for (int m = 0; m < 4; ++m)
#pragma unroll
            for (int n = 0; n < 3; ++n) {
                accR[m][n] = __builtin_amdgcn_mfma_f32_16x16x32_bf16(ar[m],  wr[n], accR[m][n], 0, 0, 0);
                accR[m][n] = __builtin_amdgcn_mfma_f32_16x16x32_bf16(ain[m], wi[n], accR[m][n], 0, 0, 0);
                accI[m][n] = __builtin_amdgcn_mfma_f32_16x16x32_bf16(ar[m],  wi[n], accI[m][n], 0, 0, 0);
                accI[m][n] = __builtin_amdgcn_mfma_f32_16x16x32_bf16(ai[m],  wr[n], accI[m][n], 0, 0, 0);
            }
    }
    __syncthreads();   // all S1 reads of x done before overwriting LDS

    // relu + store r1/i1 as bf16 (C/D layout: row=(l>>4)*4+reg, col=l&15)
#pragma unroll
    for (int m = 0; m < 4; ++m)
#pragma unroll
        for (int n = 0; n < 3; ++n)
#pragma unroll
            for (int r = 0; r < 4; ++r) {
                float rv = accR[m][n][r]; rv = rv > 0.f ? rv : 0.f;
                float iv = accI[m][n][r]; iv = iv > 0.f ? iv : 0.f;
                bufR[m * 16 + lg * 4 + r][col0 + n * 16 + lc] = f2bf(rv);
                bufI[m * 16 + lg * 4 + r][col0 + n * 16 + lc] = f2bf(iv);
            }
    __syncthreads();

    // ================= S2: r2 =================
    f32x4 acc2R[4][3];
#pragma unroll
    for (int n = 0; n < 3; ++n) {
        const float br = b2[(size_t)(0 * 4 + blk) * BLK + col0 + n * 16 + lc];
#pragma unroll
        for (int m = 0; m < 4; ++m) acc2R[m][n] = (f32x4){br, br, br, br};
    }
    for (int kk = 0; kk < 6; ++kk) {
        bf16x8 ar[4], ain[4];
#pragma unroll
        for (int m = 0; m < 4; ++m) {
            ar[m]  = *(const bf16x8*)&bufR[m * 16 + lc][kk * 32 + lg * 8];
            ain[m] = neg8(*(const bf16x8*)&bufI[m * 16 + lc][kk * 32 + lg * 8]);
        }
        bf16x8 wr[3], wi[3];
#pragma unroll
        for (int n = 0; n < 3; ++n) {
            const size_t off = ((size_t)(kk * 12 + wv * 3 + n) * 64 + l) * 8;
            wr[n] = *(const bf16x8*)(pW2r + off);
            wi[n] = *(const bf16x8*)(pW2i + off);
        }
#pragma unroll
        for (int m = 0; m < 4; ++m)
#pragma unroll
            for (int n = 0; n < 3; ++n) {
                acc2R[m][n] = __builtin_amdgcn_mfma_f32_16x16x32_bf16(ar[m],  wr[n], acc2R[m][n], 0, 0, 0);
                acc2R[m][n] = __builtin_amdgcn_mfma_f32_16x16x32_bf16(ain[m], wi[n], acc2R[m][n], 0, 0, 0);
            }
    }
    __syncthreads();   // all S2 reads of r1 done

    // store r2 (overwrites r1 buffer)
#pragma unroll
    for (int m = 0; m < 4; ++m)
#pragma unroll
        for (int n = 0; n < 3; ++n)
#pragma unroll
            for (int r = 0; r < 4; ++r)
                bufR[m * 16 + lg * 4 + r][col0 + n * 16 + lc] = f2bf(acc2R[m][n][r]);
    __syncthreads();

    // ================= S3: i2 (uses updated r2) =================
    f32x4 acc2I[4][3];
#pragma unroll
    for (int n = 0; n < 3; ++n) {
        const float bi = b2[(size_t)(1 * 4 + blk) * BLK + col0 + n * 16 + lc];
#pragma unroll
        for (int m = 0; m < 4; ++m) acc2I[m][n] = (f32x4){bi, bi, bi, bi};
    }
    for (int kk = 0; kk < 6; ++kk) {
        bf16x8 a2[4], i1[4];
#pragma unroll
        for (int m = 0; m < 4; ++m) {
            a2[m] = *(const bf16x8*)&bufR[m * 16 + lc][kk * 32 + lg * 8];  // r2
            i1[m] = *(const bf16x8*)&bufI[m * 16 + lc][kk * 32 + lg * 8];  // i1
        }
        bf16x8 wr[3], wi[3];
#pragma unroll
        for (int n = 0; n < 3; ++n) {
            const size_t off = ((size_t)(kk * 12 + wv * 3 + n) * 64 + l) * 8;
            wr[n] = *(const bf16x8*)(pW2r + off);
            wi[n] = *(const bf16x8*)(pW2i + off);
        }
#pragma unroll
        for (int m = 0; m < 4; ++m)
#pragma unroll
            for (int n = 0; n < 3; ++n) {
                acc2I[m][n] = __builtin_amdgcn_mfma_f32_16x16x32_bf16(a2[m], wi[n], acc2I[m][n], 0, 0, 0);
                acc2I[m][n] = __builtin_amdgcn_mfma_f32_16x16x32_bf16(i1[m], wr[n], acc2I[m][n], 0, 0, 0);
            }
    }

    // ---- write r2 / i2 back to global (fp32, in place) ----
#pragma unroll
    for (int m = 0; m < 4; ++m)
#pragma unroll
        for (int n = 0; n < 3; ++n)
#pragma unroll
            for (int r = 0; r < 4; ++r) {
                const int point = pt0 + m * 16 + lg * 4 + r;
                if (point < P) {
                    const size_t g = (size_t)point * CC + blk * BLK + col0 + n * 16 + lc;
                    Xr[g] = acc2R[m][n][r];
                    Xi[g] = acc2I[m][n][r];
                }
            }
}

// ---------------------------------------------------------------------------
// Stage 5: inverse real FFT along W.
// ---------------------------------------------------------------------------
__global__ __launch_bounds__(256) void k_irfft_w(const float* __restrict__ Xr,
                                                 const float* __restrict__ Xi,
                                                 float* __restrict__ out) {
    const int bid = blockIdx.x;
    const int bh  = bid / 3;
    const int c   = (bid % 3) * 256 + threadIdx.x;

    const size_t ibase = (size_t)bh * WF * CC + c;
    float xr[17], xi[17];
#pragma unroll
    for (int k = 0; k < 17; ++k) {
        xr[k] = Xr[ibase + (size_t)k * CC];
        xi[k] = Xi[ibase + (size_t)k * CC];
    }
    float* po = out + (size_t)bh * Ww * CC + c;
#pragma unroll
    for (int w = 0; w < 32; ++w) {
        float s = xr[0] + ((w & 1) ? -xr[16] : xr[16]);
#pragma unroll
        for (int k = 1; k <= 15; ++k) {
            const int t = (k * w) & 31;
            s = fmaf(2.f * xr[k],  C32[t], s);
            s = fmaf(2.f * xi[k], -S32[t], s);
        }
        po[(size_t)w * CC] = s * 0.03125f;
    }
}

// ---------------------------------------------------------------------------
extern "C" void kernel_launch(void* const* d_in, const int* in_sizes, int n_in,
                              void* d_out, int out_size, void* d_ws, size_t ws_size,
                              hipStream_t stream) {
    const float* x  = (const float*)d_in[0];
    const float* w1 = (const float*)d_in[1];
    const float* b1 = (const float*)d_in[2];
    const float* w2 = (const float*)d_in[3];
    const float* b2 = (const float*)d_in[4];
    float* out = (float*)d_out;

    // ws layout: [packed bf16 weights | Xr | Xi]
    ushort* pw = (ushort*)d_ws;
    float* base = (float*)((char*)d_ws + PW_BYTES);
    const size_t wsAvail = (ws_size > PW_BYTES) ? (ws_size - PW_BYTES) : 0;

    int chunkB = BATCH;
    while (chunkB > 1 &&
           (size_t)2 * chunkB * PTS_PER_B * CC * sizeof(float) > wsAvail)
        chunkB >>= 1;

    float* Xr = base;
    float* Xi = base + (size_t)chunkB * PTS_PER_B * CC;

    k_pack<<<dim3(2304), dim3(256), 0, stream>>>(w1, w2, pw);

    for (int b0 = 0; b0 < BATCH; b0 += chunkB) {
        const float* xc = x   + (size_t)b0 * (Hh * Ww) * CC;
        float*       oc = out + (size_t)b0 * (Hh * Ww) * CC;
        const int P = chunkB * PTS_PER_B;
        const int numM = (P + 63) / 64;

        k_rfft_w<<<dim3(chunkB * Hh * 3), dim3(256), 0, stream>>>(xc, Xr, Xi);
        k_fft_h<false><<<dim3(chunkB * WF * 3), dim3(256), 0, stream>>>(Xr, Xi);
        k_mix_mfma<<<dim3(numM * 4), dim3(256), 0, stream>>>(Xr, Xi, pw, b1, b2, P);
        k_fft_h<true><<<dim3(chunkB * WF * 3), dim3(256), 0, stream>>>(Xr, Xi);
        k_irfft_w<<<dim3(chunkB * Hh * 3), dim3(256), 0, stream>>>(Xr, Xi, oc);
    }
}

// Round 3
// 254.601 us; speedup vs baseline: 6.5634x; 2.1713x over previous
//
#include <hip/hip_runtime.h>
#include <cstddef>
#include <cstdint>

// ---------------------------------------------------------------------------
// AFNO: rfft2(32x32, ortho) -> block-diag complex 2-layer MLP -> irfft2
// Round 3: 3-kernel pipeline, bf16 spectrum in ws, H-FFT done as MFMA GEMMs
// fused with the mix:   k_rfft_w -> k_fft_mix (fftH+S1+S2+S3+ifftH) -> k_irfft_w
// ---------------------------------------------------------------------------

typedef __attribute__((ext_vector_type(8))) short bf16x8;
typedef __attribute__((ext_vector_type(4))) float f32x4;

namespace {

constexpr int BATCH = 64;
constexpr int Hh    = 32;
constexpr int Ww    = 32;
constexpr int WF    = 17;   // 32/2 + 1
constexpr int CC    = 768;
constexpr int BLK   = 192;

constexpr size_t W_ELEMS  = 16u * 36864u;          // 16 packed 192x192 bf16 mats
constexpr size_t TW_ELEMS = 4u * 1024u;            // 4 packed 32x32 twiddle mats
constexpr size_t PW_ELEMS = W_ELEMS + TW_ELEMS;    // 593920
constexpr size_t SPEC_ELEMS = (size_t)BATCH * WF * Hh * CC;  // 26,738,688

// twiddles: C32[j] = cos(2*pi*j/32), S32[j] = sin(2*pi*j/32)
constexpr float C32[32] = {
   1.0000000000f,  0.9807852804f,  0.9238795325f,  0.8314696123f,
   0.7071067812f,  0.5555702330f,  0.3826834324f,  0.1950903220f,
   0.0000000000f, -0.1950903220f, -0.3826834324f, -0.5555702330f,
  -0.7071067812f, -0.8314696123f, -0.9238795325f, -0.9807852804f,
  -1.0000000000f, -0.9807852804f, -0.9238795325f, -0.8314696123f,
  -0.7071067812f, -0.5555702330f, -0.3826834324f, -0.1950903220f,
   0.0000000000f,  0.1950903220f,  0.3826834324f,  0.5555702330f,
   0.7071067812f,  0.8314696123f,  0.9238795325f,  0.9807852804f
};
constexpr float S32[32] = {
   0.0000000000f,  0.1950903220f,  0.3826834324f,  0.5555702330f,
   0.7071067812f,  0.8314696123f,  0.9238795325f,  0.9807852804f,
   1.0000000000f,  0.9807852804f,  0.9238795325f,  0.8314696123f,
   0.7071067812f,  0.5555702330f,  0.3826834324f,  0.1950903220f,
   0.0000000000f, -0.1950903220f, -0.3826834324f, -0.5555702330f,
  -0.7071067812f, -0.8314696123f, -0.9238795325f, -0.9807852804f,
  -1.0000000000f, -0.9807852804f, -0.9238795325f, -0.8314696123f,
  -0.7071067812f, -0.5555702330f, -0.3826834324f, -0.1950903220f
};

} // namespace

__device__ __forceinline__ ushort f2bf(float f) {
    union { float f; unsigned u; } v; v.f = f;
    const unsigned r = (v.u + 0x7FFFu + ((v.u >> 16) & 1u)) >> 16;
    return (ushort)r;
}
__device__ __forceinline__ float bf2f(ushort u) {
    union { unsigned u; float f; } v; v.u = ((unsigned)u) << 16;
    return v.f;
}
__device__ __forceinline__ bf16x8 neg8(bf16x8 a) {
    union { bf16x8 v; uint4 u; } t; t.v = a;
    t.u.x ^= 0x80008000u; t.u.y ^= 0x80008000u;
    t.u.z ^= 0x80008000u; t.u.w ^= 0x80008000u;
    return t.v;
}

// ---------------------------------------------------------------------------
// Pre-pack: weights (B-frag layout, as round 2) + 4 twiddle mats (A-frag layout)
//   weights: pw[mi][kk][nf][lane][i], d = kk*32+(lane>>4)*8+i, col = nf*16+(lane&15)
//   twiddle: TW[mat][mf][lane][i],  row = mf*16+(lane&15), col = (lane>>4)*8+i
//     mat0 = C/32, mat1 = S/32 (fwd, ortho-scaled), mat2 = C, mat3 = S (inv)
// ---------------------------------------------------------------------------
__global__ __launch_bounds__(256) void k_pack(const float* __restrict__ w1,
                                              const float* __restrict__ w2,
                                              ushort* __restrict__ pw) {
    const unsigned idx = blockIdx.x * 256u + threadIdx.x;   // 0 .. 593919
    if (idx < W_ELEMS) {
        const unsigned mi = idx / 36864u;       // which*4 + blk
        const unsigned r  = idx % 36864u;
        const unsigned kk = r / 6144u;
        const unsigned r2 = r % 6144u;
        const unsigned nf = r2 / 512u;
        const unsigned r3 = r2 % 512u;
        const unsigned lane = r3 / 8u;
        const unsigned i  = r3 % 8u;
        const unsigned d   = kk * 32u + (lane >> 4) * 8u + i;
        const unsigned col = nf * 16u + (lane & 15u);
        const unsigned which = mi >> 2, blk = mi & 3u;
        const float* src = (which < 2u)
            ? (w1 + (size_t)(which * 4u + blk) * BLK * BLK)
            : (w2 + (size_t)((which - 2u) * 4u + blk) * BLK * BLK);
        pw[idx] = f2bf(src[(size_t)d * BLK + col]);
    } else {
        const unsigned t = idx - (unsigned)W_ELEMS;   // 0..4095
        const unsigned mat = t >> 10;
        const unsigned rr  = t & 1023u;
        const unsigned mf  = rr >> 9;
        const unsigned q   = rr & 511u;
        const unsigned lane = q >> 3, i = q & 7u;
        const unsigned row = mf * 16u + (lane & 15u);
        const unsigned col = (lane >> 4) * 8u + i;
        const unsigned ang = (row * col) & 31u;
        float v;
        if      (mat == 0u) v = C32[ang] * 0.03125f;
        else if (mat == 1u) v = S32[ang] * 0.03125f;
        else if (mat == 2u) v = C32[ang];
        else                v = S32[ang];
        pw[idx] = f2bf(v);
    }
}

// ---------------------------------------------------------------------------
// Stage 1: real FFT along W (fp32 compute, bf16 output spectrum).
// spec layout: [b][kw][h][c]   (c fastest)
// even/odd pairing: sr(k)=v0+(-1)^k v16 + sum a_w cos;  si(k)=-sum b_w sin
// ---------------------------------------------------------------------------
__global__ __launch_bounds__(256) void k_rfft_w(const float* __restrict__ x,
                                                ushort* __restrict__ sRe,
                                                ushort* __restrict__ sIm) {
    const int bid = blockIdx.x;
    const int bh  = bid / 3;
    const int c   = (bid % 3) * 256 + threadIdx.x;

    const float* px = x + (size_t)bh * Ww * CC + c;
    float v[32];
#pragma unroll
    for (int w = 0; w < 32; ++w) v[w] = px[(size_t)w * CC];

    float av[16], bv[16];
#pragma unroll
    for (int w = 1; w <= 15; ++w) { av[w] = v[w] + v[32 - w]; bv[w] = v[w] - v[32 - w]; }

    const int b = bh >> 5, h = bh & 31;
    const size_t ob = ((size_t)b * WF * Hh + h) * CC + c;   // + kw*Hh*CC
#pragma unroll
    for (int k = 0; k <= 16; ++k) {
        float sr = v[0] + ((k & 1) ? -v[16] : v[16]);
        float si = 0.f;
#pragma unroll
        for (int w = 1; w <= 15; ++w) {
            const int t = (k * w) & 31;
            sr = fmaf(av[w],  C32[t], sr);
            si = fmaf(bv[w], -S32[t], si);
        }
        sRe[ob + (size_t)k * Hh * CC] = f2bf(sr);
        sIm[ob + (size_t)k * Hh * CC] = f2bf(si);
    }
}

// ---------------------------------------------------------------------------
// Stage 2 (fused): per (b,kw,blk) tile [32h x 192c]:
//   P1: Y = F_h X        (MFMA, twiddle A-frags, scale 1/32)
//   P2: r1,i1 = relu(Y W1 + b1)          (complex)
//   P3: r2 = r1 W2r - i1 W2i + b2r
//   P4: i2 = r2 W2i + i1 W2r + b2i       (updated r2, per reference)
//   P5: Z = F_h^{-1} (r2 + i i2)         (MFMA), write back bf16 in place
// LDS planes [32][200] bf16: 0 Xr(->r2) 1 Xi(->i2) 2 Yr 3 Yi 4 r1 5 i1
// ---------------------------------------------------------------------------
__device__ __forceinline__ bf16x8 gatherB(const ushort* pl, int col, int lg) {
    union { bf16x8 v; ushort u[8]; } t;
#pragma unroll
    for (int i = 0; i < 8; ++i) t.u[i] = pl[(lg * 8 + i) * 200 + col];
    return t.v;
}

__global__ __launch_bounds__(256) void k_fft_mix(
        ushort* __restrict__ sRe, ushort* __restrict__ sIm,
        const ushort* __restrict__ pw,
        const float* __restrict__ b1, const float* __restrict__ b2) {

    __shared__ ushort lds[6][32][200];

    const int bid = blockIdx.x;
    const int blk = bid / (BATCH * WF);       // slowest: weight locality
    const int rem = bid % (BATCH * WF);
    const int b   = rem / WF;
    const int kw  = rem % WF;
    const int tid = threadIdx.x;
    const int wv = tid >> 6, l = tid & 63, lc = l & 15, lg = l >> 4;

    const size_t gbase = ((size_t)b * WF + kw) * Hh * CC + blk * BLK;  // + h*CC + c

    // ---- load X tile (bf16) ----
#pragma unroll
    for (int j = 0; j < 3; ++j) {
        const int q = tid + 256 * j;          // 0..767 : 16B chunks
        const int h = q / 24, c8 = (q % 24) * 8;
        const uint4 vr = *(const uint4*)(sRe + gbase + (size_t)h * CC + c8);
        const uint4 vi = *(const uint4*)(sIm + gbase + (size_t)h * CC + c8);
        *(uint4*)&lds[0][h][c8] = vr;
        *(uint4*)&lds[1][h][c8] = vi;
    }
    __syncthreads();

    const ushort* TW = pw + W_ELEMS;
    const int col0 = wv * 48;

    // ================= P1: forward H-FFT =================
    {
        bf16x8 cf[2], sf[2], sfn[2];
#pragma unroll
        for (int m = 0; m < 2; ++m) {
            cf[m]  = *(const bf16x8*)(TW + ((size_t)(0 * 2 + m) * 64 + l) * 8);
            sf[m]  = *(const bf16x8*)(TW + ((size_t)(1 * 2 + m) * 64 + l) * 8);
            sfn[m] = neg8(sf[m]);
        }
        bf16x8 xr[3], xi[3];
#pragma unroll
        for (int n = 0; n < 3; ++n) {
            xr[n] = gatherB(&lds[0][0][0], col0 + n * 16 + lc, lg);
            xi[n] = gatherB(&lds[1][0][0], col0 + n * 16 + lc, lg);
        }
        f32x4 yr[2][3] = {}, yi[2][3] = {};
#pragma unroll
        for (int m = 0; m < 2; ++m)
#pragma unroll
            for (int n = 0; n < 3; ++n) {
                yr[m][n] = __builtin_amdgcn_mfma_f32_16x16x32_bf16(cf[m],  xr[n], yr[m][n], 0, 0, 0);
                yr[m][n] = __builtin_amdgcn_mfma_f32_16x16x32_bf16(sf[m],  xi[n], yr[m][n], 0, 0, 0);
                yi[m][n] = __builtin_amdgcn_mfma_f32_16x16x32_bf16(cf[m],  xi[n], yi[m][n], 0, 0, 0);
                yi[m][n] = __builtin_amdgcn_mfma_f32_16x16x32_bf16(sfn[m], xr[n], yi[m][n], 0, 0, 0);
            }
#pragma unroll
        for (int m = 0; m < 2; ++m)
#pragma unroll
            for (int n = 0; n < 3; ++n)
#pragma unroll
                for (int r = 0; r < 4; ++r) {
                    lds[2][m * 16 + lg * 4 + r][col0 + n * 16 + lc] = f2bf(yr[m][n][r]);
                    lds[3][m * 16 + lg * 4 + r][col0 + n * 16 + lc] = f2bf(yi[m][n][r]);
                }
    }
    __syncthreads();

    const ushort* pW1r = pw + (size_t)(0 * 4 + blk) * 36864;
    const ushort* pW1i = pw + (size_t)(1 * 4 + blk) * 36864;
    const ushort* pW2r = pw + (size_t)(2 * 4 + blk) * 36864;
    const ushort* pW2i = pw + (size_t)(3 * 4 + blk) * 36864;

    // ================= P2: layer 1 + relu =================
    {
        f32x4 aR[2][3], aI[2][3];
#pragma unroll
        for (int n = 0; n < 3; ++n) {
            const float br = b1[(size_t)(0 * 4 + blk) * BLK + col0 + n * 16 + lc];
            const float bi = b1[(size_t)(1 * 4 + blk) * BLK + col0 + n * 16 + lc];
#pragma unroll
            for (int m = 0; m < 2; ++m) {
                aR[m][n] = (f32x4){br, br, br, br};
                aI[m][n] = (f32x4){bi, bi, bi, bi};
            }
        }
#pragma unroll
        for (int kk = 0; kk < 6; ++kk) {
            bf16x8 ar[2], ai[2], ain[2];
#pragma unroll
            for (int m = 0; m < 2; ++m) {
                ar[m]  = *(const bf16x8*)&lds[2][m * 16 + lc][kk * 32 + lg * 8];
                ai[m]  = *(const bf16x8*)&lds[3][m * 16 + lc][kk * 32 + lg * 8];
                ain[m] = neg8(ai[m]);
            }
            bf16x8 wr[3], wi[3];
#pragma unroll
            for (int n = 0; n < 3; ++n) {
                const size_t off = ((size_t)(kk * 12 + wv * 3 + n) * 64 + l) * 8;
                wr[n] = *(const bf16x8*)(pW1r + off);
                wi[n] = *(const bf16x8*)(pW1i + off);
            }
#pragma unroll
            for (int m = 0; m < 2; ++m)
#pragma unroll
                for (int n = 0; n < 3; ++n) {
                    aR[m][n] = __builtin_amdgcn_mfma_f32_16x16x32_bf16(ar[m],  wr[n], aR[m][n], 0, 0, 0);
                    aR[m][n] = __builtin_amdgcn_mfma_f32_16x16x32_bf16(ain[m], wi[n], aR[m][n], 0, 0, 0);
                    aI[m][n] = __builtin_amdgcn_mfma_f32_16x16x32_bf16(ar[m],  wi[n], aI[m][n], 0, 0, 0);
                    aI[m][n] = __builtin_amdgcn_mfma_f32_16x16x32_bf16(ai[m],  wr[n], aI[m][n], 0, 0, 0);
                }
        }
#pragma unroll
        for (int m = 0; m < 2; ++m)
#pragma unroll
            for (int n = 0; n < 3; ++n)
#pragma unroll
                for (int r = 0; r < 4; ++r) {
                    float rv = aR[m][n][r]; rv = rv > 0.f ? rv : 0.f;
                    float iv = aI[m][n][r]; iv = iv > 0.f ? iv : 0.f;
                    lds[4][m * 16 + lg * 4 + r][col0 + n * 16 + lc] = f2bf(rv);
                    lds[5][m * 16 + lg * 4 + r][col0 + n * 16 + lc] = f2bf(iv);
                }
    }
    __syncthreads();

    // ================= P3: r2 =================
    {
        f32x4 cR[2][3];
#pragma unroll
        for (int n = 0; n < 3; ++n) {
            const float br = b2[(size_t)(0 * 4 + blk) * BLK + col0 + n * 16 + lc];
#pragma unroll
            for (int m = 0; m < 2; ++m) cR[m][n] = (f32x4){br, br, br, br};
        }
#pragma unroll
        for (int kk = 0; kk < 6; ++kk) {
            bf16x8 ar[2], ain[2];
#pragma unroll
            for (int m = 0; m < 2; ++m) {
                ar[m]  = *(const bf16x8*)&lds[4][m * 16 + lc][kk * 32 + lg * 8];
                ain[m] = neg8(*(const bf16x8*)&lds[5][m * 16 + lc][kk * 32 + lg * 8]);
            }
            bf16x8 wr[3], wi[3];
#pragma unroll
            for (int n = 0; n < 3; ++n) {
                const size_t off = ((size_t)(kk * 12 + wv * 3 + n) * 64 + l) * 8;
                wr[n] = *(const bf16x8*)(pW2r + off);
                wi[n] = *(const bf16x8*)(pW2i + off);
            }
#pragma unroll
            for (int m = 0; m < 2; ++m)
#pragma unroll
                for (int n = 0; n < 3; ++n) {
                    cR[m][n] = __builtin_amdgcn_mfma_f32_16x16x32_bf16(ar[m],  wr[n], cR[m][n], 0, 0, 0);
                    cR[m][n] = __builtin_amdgcn_mfma_f32_16x16x32_bf16(ain[m], wi[n], cR[m][n], 0, 0, 0);
                }
        }
#pragma unroll
        for (int m = 0; m < 2; ++m)
#pragma unroll
            for (int n = 0; n < 3; ++n)
#pragma unroll
                for (int r = 0; r < 4; ++r)
                    lds[0][m * 16 + lg * 4 + r][col0 + n * 16 + lc] = f2bf(cR[m][n][r]);
    }
    __syncthreads();

    // ================= P4: i2 (uses updated r2) =================
    {
        f32x4 cI[2][3];
#pragma unroll
        for (int n = 0; n < 3; ++n) {
            const float bi = b2[(size_t)(1 * 4 + blk) * BLK + col0 + n * 16 + lc];
#pragma unroll
            for (int m = 0; m < 2; ++m) cI[m][n] = (f32x4){bi, bi, bi, bi};
        }
#pragma unroll
        for (int kk = 0; kk < 6; ++kk) {
            bf16x8 a2[2], i1[2];
#pragma unroll
            for (int m = 0; m < 2; ++m) {
                a2[m] = *(const bf16x8*)&lds[0][m * 16 + lc][kk * 32 + lg * 8];  // r2
                i1[m] = *(const bf16x8*)&lds[5][m * 16 + lc][kk * 32 + lg * 8];  // i1
            }
            bf16x8 wr[3], wi[3];
#pragma unroll
            for (int n = 0; n < 3; ++n) {
                const size_t off = ((size_t)(kk * 12 + wv * 3 + n) * 64 + l) * 8;
                wr[n] = *(const bf16x8*)(pW2r + off);
                wi[n] = *(const bf16x8*)(pW2i + off);
            }
#pragma unroll
            for (int m = 0; m < 2; ++m)
#pragma unroll
                for (int n = 0; n < 3; ++n) {
                    cI[m][n] = __builtin_amdgcn_mfma_f32_16x16x32_bf16(a2[m], wi[n], cI[m][n], 0, 0, 0);
                    cI[m][n] = __builtin_amdgcn_mfma_f32_16x16x32_bf16(i1[m], wr[n], cI[m][n], 0, 0, 0);
                }
        }
#pragma unroll
        for (int m = 0; m < 2; ++m)
#pragma unroll
            for (int n = 0; n < 3; ++n)
#pragma unroll
                for (int r = 0; r < 4; ++r)
                    lds[1][m * 16 + lg * 4 + r][col0 + n * 16 + lc] = f2bf(cI[m][n][r]);
    }
    __syncthreads();

    // ================= P5: inverse H-FFT + store =================
    {
        bf16x8 ci[2], si[2], sin_[2];
#pragma unroll
        for (int m = 0; m < 2; ++m) {
            ci[m]   = *(const bf16x8*)(TW + ((size_t)(2 * 2 + m) * 64 + l) * 8);
            si[m]   = *(const bf16x8*)(TW + ((size_t)(3 * 2 + m) * 64 + l) * 8);
            sin_[m] = neg8(si[m]);
        }
        bf16x8 r2b[3], i2b[3];
#pragma unroll
        for (int n = 0; n < 3; ++n) {
            r2b[n] = gatherB(&lds[0][0][0], col0 + n * 16 + lc, lg);
            i2b[n] = gatherB(&lds[1][0][0], col0 + n * 16 + lc, lg);
        }
        f32x4 zr[2][3] = {}, zi[2][3] = {};
#pragma unroll
        for (int m = 0; m < 2; ++m)
#pragma unroll
            for (int n = 0; n < 3; ++n) {
                zr[m][n] = __builtin_amdgcn_mfma_f32_16x16x32_bf16(ci[m],   r2b[n], zr[m][n], 0, 0, 0);
                zr[m][n] = __builtin_amdgcn_mfma_f32_16x16x32_bf16(sin_[m], i2b[n], zr[m][n], 0, 0, 0);
                zi[m][n] = __builtin_amdgcn_mfma_f32_16x16x32_bf16(ci[m],   i2b[n], zi[m][n], 0, 0, 0);
                zi[m][n] = __builtin_amdgcn_mfma_f32_16x16x32_bf16(si[m],   r2b[n], zi[m][n], 0, 0, 0);
            }
#pragma unroll
        for (int m = 0; m < 2; ++m)
#pragma unroll
            for (int n = 0; n < 3; ++n)
#pragma unroll
                for (int r = 0; r < 4; ++r) {
                    const int row = m * 16 + lg * 4 + r;
                    const size_t g = gbase + (size_t)row * CC + col0 + n * 16 + lc;
                    sRe[g] = f2bf(zr[m][n][r]);
                    sIm[g] = f2bf(zi[m][n][r]);
                }
    }
}

// ---------------------------------------------------------------------------
// Stage 3: inverse real FFT along W (bf16 spectrum in, fp32 out).
//   e(w) = xr0 + (-1)^w xr16 + sum 2 xr_k cos ;  o(w) = -sum 2 xi_k sin
//   out[w] = (e+o)/32 ; out[32-w] = (e-o)/32
// ---------------------------------------------------------------------------
__global__ __launch_bounds__(256) void k_irfft_w(const ushort* __restrict__ sRe,
                                                 const ushort* __restrict__ sIm,
                                                 float* __restrict__ out) {
    const int bid = blockIdx.x;
    const int bh  = bid / 3;
    const int c   = (bid % 3) * 256 + threadIdx.x;
    const int b = bh >> 5, h = bh & 31;

    const size_t ib = ((size_t)b * WF * Hh + h) * CC + c;
    float xr[17], xi[17];
#pragma unroll
    for (int k = 0; k < 17; ++k) {
        xr[k] = bf2f(sRe[ib + (size_t)k * Hh * CC]);
        xi[k] = bf2f(sIm[ib + (size_t)k * Hh * CC]);
    }
    float* po = out + (size_t)bh * Ww * CC + c;
#pragma unroll
    for (int w = 0; w <= 16; ++w) {
        float e = xr[0] + ((w & 1) ? -xr[16] : xr[16]);
        float o = 0.f;
#pragma unroll
        for (int k = 1; k <= 15; ++k) {
            const int t = (k * w) & 31;
            e = fmaf(2.f * xr[k],  C32[t], e);
            o = fmaf(2.f * xi[k], -S32[t], o);
        }
        po[(size_t)w * CC] = (e + o) * 0.03125f;
        if (w >= 1 && w <= 15)
            po[(size_t)(32 - w) * CC] = (e - o) * 0.03125f;
    }
}

// ---------------------------------------------------------------------------
extern "C" void kernel_launch(void* const* d_in, const int* in_sizes, int n_in,
                              void* d_out, int out_size, void* d_ws, size_t ws_size,
                              hipStream_t stream) {
    const float* x  = (const float*)d_in[0];
    const float* w1 = (const float*)d_in[1];
    const float* b1 = (const float*)d_in[2];
    const float* w2 = (const float*)d_in[3];
    const float* b2 = (const float*)d_in[4];
    float* out = (float*)d_out;

    ushort* pw   = (ushort*)d_ws;
    ushort* sRe  = pw + PW_ELEMS;
    ushort* sIm  = sRe + SPEC_ELEMS;

    k_pack<<<dim3((unsigned)(PW_ELEMS / 256)), dim3(256), 0, stream>>>(w1, w2, pw);
    k_rfft_w<<<dim3(BATCH * Hh * 3), dim3(256), 0, stream>>>(x, sRe, sIm);
    k_fft_mix<<<dim3(4 * BATCH * WF), dim3(256), 0, stream>>>(sRe, sIm, pw, b1, b2);
    k_irfft_w<<<dim3(BATCH * Hh * 3), dim3(256), 0, stream>>>(sRe, sIm, out);
}

// Round 4
// 253.216 us; speedup vs baseline: 6.5993x; 1.0055x over previous
//
#include <hip/hip_runtime.h>
#include <cstddef>
#include <cstdint>

// ---------------------------------------------------------------------------
// AFNO: rfft2(32x32, ortho) -> block-diag complex 2-layer MLP -> irfft2
// Round 4: subtiled/swizzled bf16 spectrum layout; k2 uses only vector LDS ops
// (b128 A-frags, 4xb32 pair-interleaved B-frags), 4 LDS regions -> 3 WG/CU.
// ---------------------------------------------------------------------------

typedef __attribute__((ext_vector_type(8))) short bf16x8;
typedef __attribute__((ext_vector_type(4))) float f32x4;

namespace {

constexpr int BATCH = 64;
constexpr int Hh    = 32;
constexpr int Ww    = 32;
constexpr int WF    = 17;   // 32/2 + 1
constexpr int CC    = 768;
constexpr int BLK   = 192;

constexpr size_t W_ELEMS  = 16u * 36864u;          // packed 192x192 bf16 mats
constexpr size_t TW_ELEMS = 4u * 1024u;            // packed 32x32 twiddles
constexpr size_t PW_ELEMS = W_ELEMS + TW_ELEMS;    // 593920 ushorts

// spectrum: [b][kw][plane(2)][csubg(48)][512]  (ushorts)
// within a 512-chunk: pos = hp*32 + ((c&15) ^ ((hp&7)<<1))*2 + (h&1)
constexpr int PLANE_U = 48 * 512;                  // 24576 ushorts per plane
constexpr size_t SPEC_ELEMS = (size_t)BATCH * WF * 2 * PLANE_U;

constexpr float C32[32] = {
   1.0000000000f,  0.9807852804f,  0.9238795325f,  0.8314696123f,
   0.7071067812f,  0.5555702330f,  0.3826834324f,  0.1950903220f,
   0.0000000000f, -0.1950903220f, -0.3826834324f, -0.5555702330f,
  -0.7071067812f, -0.8314696123f, -0.9238795325f, -0.9807852804f,
  -1.0000000000f, -0.9807852804f, -0.9238795325f, -0.8314696123f,
  -0.7071067812f, -0.5555702330f, -0.3826834324f, -0.1950903220f,
   0.0000000000f,  0.1950903220f,  0.3826834324f,  0.5555702330f,
   0.7071067812f,  0.8314696123f,  0.9238795325f,  0.9807852804f
};
constexpr float S32[32] = {
   0.0000000000f,  0.1950903220f,  0.3826834324f,  0.5555702330f,
   0.7071067812f,  0.8314696123f,  0.9238795325f,  0.9807852804f,
   1.0000000000f,  0.9807852804f,  0.9238795325f,  0.8314696123f,
   0.7071067812f,  0.5555702330f,  0.3826834324f,  0.1950903220f,
   0.0000000000f, -0.1950903220f, -0.3826834324f, -0.5555702330f,
  -0.7071067812f, -0.8314696123f, -0.9238795325f, -0.9807852804f,
  -1.0000000000f, -0.9807852804f, -0.9238795325f, -0.8314696123f,
  -0.7071067812f, -0.5555702330f, -0.3826834324f, -0.1950903220f
};

} // namespace

__device__ __forceinline__ ushort f2bf(float f) {
    union { float f; unsigned u; } v; v.f = f;
    const unsigned r = (v.u + 0x7FFFu + ((v.u >> 16) & 1u)) >> 16;
    return (ushort)r;
}
__device__ __forceinline__ float bf2f(ushort u) {
    union { unsigned u; float f; } v; v.u = ((unsigned)u) << 16;
    return v.f;
}
__device__ __forceinline__ bf16x8 neg8(bf16x8 a) {
    union { bf16x8 v; uint4 u; } t; t.v = a;
    t.u.x ^= 0x80008000u; t.u.y ^= 0x80008000u;
    t.u.z ^= 0x80008000u; t.u.w ^= 0x80008000u;
    return t.v;
}

// ---------------------------------------------------------------------------
// Pre-pack (unchanged): weights -> B-frag layout; twiddles -> A-frag layout.
// ---------------------------------------------------------------------------
__global__ __launch_bounds__(256) void k_pack(const float* __restrict__ w1,
                                              const float* __restrict__ w2,
                                              ushort* __restrict__ pw) {
    const unsigned idx = blockIdx.x * 256u + threadIdx.x;
    if (idx < W_ELEMS) {
        const unsigned mi = idx / 36864u;
        const unsigned r  = idx % 36864u;
        const unsigned kk = r / 6144u;
        const unsigned r2 = r % 6144u;
        const unsigned nf = r2 / 512u;
        const unsigned r3 = r2 % 512u;
        const unsigned lane = r3 / 8u;
        const unsigned i  = r3 % 8u;
        const unsigned d   = kk * 32u + (lane >> 4) * 8u + i;
        const unsigned col = nf * 16u + (lane & 15u);
        const unsigned which = mi >> 2, blk = mi & 3u;
        const float* src = (which < 2u)
            ? (w1 + (size_t)(which * 4u + blk) * BLK * BLK)
            : (w2 + (size_t)((which - 2u) * 4u + blk) * BLK * BLK);
        pw[idx] = f2bf(src[(size_t)d * BLK + col]);
    } else if (idx < PW_ELEMS) {
        const unsigned t = idx - (unsigned)W_ELEMS;
        const unsigned mat = t >> 10;
        const unsigned rr  = t & 1023u;
        const unsigned mf  = rr >> 9;
        const unsigned q   = rr & 511u;
        const unsigned lane = q >> 3, i = q & 7u;
        const unsigned row = mf * 16u + (lane & 15u);
        const unsigned col = (lane >> 4) * 8u + i;
        const unsigned ang = (row * col) & 31u;
        float v;
        if      (mat == 0u) v = C32[ang] * 0.03125f;
        else if (mat == 1u) v = S32[ang] * 0.03125f;
        else if (mat == 2u) v = C32[ang];
        else                v = S32[ang];
        pw[idx] = f2bf(v);
    }
}

// ---------------------------------------------------------------------------
// k1: real FFT along W. WG = (b, h-pair, c-chunk). Writes u32 (h0,h1 bf16 pair)
// into the swizzled spectrum layout -> fully dense coalesced stores.
// ---------------------------------------------------------------------------
__global__ __launch_bounds__(256) void k_rfft_w(const float* __restrict__ x,
                                                ushort* __restrict__ spec) {
    const int bid = blockIdx.x;
    const int cc = bid % 3;
    const int hp = (bid / 3) & 15;
    const int b  = bid / 48;
    const int c  = cc * 256 + threadIdx.x;

    uint pr[17], pi[17];
    const float* p0 = x + ((size_t)b * 1024 + hp * 64) * CC + c;
#pragma unroll
    for (int half = 0; half < 2; ++half) {
        const float* px = p0 + (size_t)half * 32 * CC;
        float v[32];
#pragma unroll
        for (int w = 0; w < 32; ++w) v[w] = px[(size_t)w * CC];
        float av[16], bv[16];
#pragma unroll
        for (int w = 1; w <= 15; ++w) { av[w] = v[w] + v[32 - w]; bv[w] = v[w] - v[32 - w]; }
#pragma unroll
        for (int k = 0; k <= 16; ++k) {
            float sr = v[0] + ((k & 1) ? -v[16] : v[16]);
            float si = 0.f;
#pragma unroll
            for (int w = 1; w <= 15; ++w) {
                const int t = (k * w) & 31;
                sr = fmaf(av[w],  C32[t], sr);
                si = fmaf(bv[w], -S32[t], si);
            }
            if (half == 0) { pr[k] = f2bf(sr); pi[k] = f2bf(si); }
            else { pr[k] |= (uint)f2bf(sr) << 16; pi[k] |= (uint)f2bf(si) << 16; }
        }
    }
    const size_t base = (size_t)b * (WF * 2 * PLANE_U)
                      + (size_t)(c >> 4) * 512 + hp * 32
                      + (((c & 15) ^ ((hp & 7) << 1)) << 1);
#pragma unroll
    for (int k = 0; k <= 16; ++k) {
        *(uint*)(spec + base + (size_t)k * (2 * PLANE_U)) = pr[k];
        *(uint*)(spec + base + (size_t)k * (2 * PLANE_U) + PLANE_U) = pi[k];
    }
}

// ---------------------------------------------------------------------------
// k2: fused fftH + S1 + S2 + S3 + ifftH, per (blk, b, kw) tile.
// LDS: 4 regions of 6336 ushorts (12 csub x 528):
//  R0: Xr(sub/ilv) -> Yr(sub) -> r2(sub)
//  R1: Xi(sub/ilv) -> Yi(sub) -> r2_t(ilv)
//  R2: r1(sub)     -> i2_t(ilv)
//  R3: i1(sub)
// sub  layout: pos = csub*528 + kh*16 + (c&15)
// ilv  layout: pos = csub*528 + hp*32 + ((c&15)^((hp&7)<<1))*2 + (k&1)
// ---------------------------------------------------------------------------
__global__ __launch_bounds__(256, 3) void k_fft_mix(
        ushort* __restrict__ spec,
        const ushort* __restrict__ pw,
        const float* __restrict__ b1, const float* __restrict__ b2) {

    __shared__ ushort lds[4][6336];

    const int bid = blockIdx.x;
    const int blk = bid / (BATCH * WF);
    const int rem = bid % (BATCH * WF);
    const int b   = rem / WF;
    const int kw  = rem % WF;
    const int tid = threadIdx.x;
    const int wv = tid >> 6, l = tid & 63, lc = l & 15, lg = l >> 4;

    const size_t gR = ((size_t)(b * WF + kw) * 2) * PLANE_U + blk * 6144;
    const size_t gI = gR + PLANE_U;

    // ---- cooperative load: contiguous copy, csub-padded ----
#pragma unroll
    for (int j = 0; j < 3; ++j) {
        const int q = tid + 256 * j;            // 0..767 16B-chunks per plane
        const int dst = (q >> 6) * 528 + (q & 63) * 8;
        *(uint4*)&lds[0][dst] = *(const uint4*)(spec + gR + q * 8);
        *(uint4*)&lds[1][dst] = *(const uint4*)(spec + gI + q * 8);
    }
    __syncthreads();

    const ushort* TW = pw + W_ELEMS;
    const int col0 = wv * 48;

    // ================= P1: forward H-FFT (in-place over X, stripe-local) ====
    {
        bf16x8 xr[3], xi[3];
#pragma unroll
        for (int n = 0; n < 3; ++n) {
            const int csub = wv * 3 + n;
            union { bf16x8 v; uint d[4]; } ur, ui;
#pragma unroll
            for (int t = 0; t < 4; ++t) {
                const int hp = lg * 4 + t;
                const int pos = csub * 528 + hp * 32 + ((lc ^ ((hp & 7) << 1)) << 1);
                ur.d[t] = *(const uint*)&lds[0][pos];
                ui.d[t] = *(const uint*)&lds[1][pos];
            }
            xr[n] = ur.v; xi[n] = ui.v;
        }
        bf16x8 cf[2], sf[2], sfn[2];
#pragma unroll
        for (int m = 0; m < 2; ++m) {
            cf[m]  = *(const bf16x8*)(TW + ((size_t)(0 * 2 + m) * 64 + l) * 8);
            sf[m]  = *(const bf16x8*)(TW + ((size_t)(1 * 2 + m) * 64 + l) * 8);
            sfn[m] = neg8(sf[m]);
        }
        f32x4 yr[2][3] = {}, yi[2][3] = {};
#pragma unroll
        for (int m = 0; m < 2; ++m)
#pragma unroll
            for (int n = 0; n < 3; ++n) {
                yr[m][n] = __builtin_amdgcn_mfma_f32_16x16x32_bf16(cf[m],  xr[n], yr[m][n], 0, 0, 0);
                yr[m][n] = __builtin_amdgcn_mfma_f32_16x16x32_bf16(sf[m],  xi[n], yr[m][n], 0, 0, 0);
                yi[m][n] = __builtin_amdgcn_mfma_f32_16x16x32_bf16(cf[m],  xi[n], yi[m][n], 0, 0, 0);
                yi[m][n] = __builtin_amdgcn_mfma_f32_16x16x32_bf16(sfn[m], xr[n], yi[m][n], 0, 0, 0);
            }
#pragma unroll
        for (int m = 0; m < 2; ++m)
#pragma unroll
            for (int n = 0; n < 3; ++n)
#pragma unroll
                for (int r = 0; r < 4; ++r) {
                    const int pos = (wv * 3 + n) * 528 + (m * 16 + lg * 4 + r) * 16 + lc;
                    lds[0][pos] = f2bf(yr[m][n][r]);
                    lds[1][pos] = f2bf(yi[m][n][r]);
                }
    }
    __syncthreads();

    const ushort* pW1r = pw + (size_t)(0 * 4 + blk) * 36864;
    const ushort* pW1i = pw + (size_t)(1 * 4 + blk) * 36864;
    const ushort* pW2r = pw + (size_t)(2 * 4 + blk) * 36864;
    const ushort* pW2i = pw + (size_t)(3 * 4 + blk) * 36864;

    // ================= P2: layer 1 + relu =================
    {
        f32x4 aR[2][3], aI[2][3];
#pragma unroll
        for (int n = 0; n < 3; ++n) {
            const float br = b1[(size_t)(0 * 4 + blk) * BLK + col0 + n * 16 + lc];
            const float bi = b1[(size_t)(1 * 4 + blk) * BLK + col0 + n * 16 + lc];
#pragma unroll
            for (int m = 0; m < 2; ++m) {
                aR[m][n] = (f32x4){br, br, br, br};
                aI[m][n] = (f32x4){bi, bi, bi, bi};
            }
        }
#pragma unroll
        for (int kk = 0; kk < 6; ++kk) {
            const int csubA = 2 * kk + (lg >> 1);
            const int apos  = csubA * 528 + lc * 16 + (lg & 1) * 8;
            bf16x8 ar[2], ai[2], ain[2];
#pragma unroll
            for (int m = 0; m < 2; ++m) {
                ar[m]  = *(const bf16x8*)&lds[0][apos + m * 256];
                ai[m]  = *(const bf16x8*)&lds[1][apos + m * 256];
                ain[m] = neg8(ai[m]);
            }
            bf16x8 wr[3], wi[3];
#pragma unroll
            for (int n = 0; n < 3; ++n) {
                const size_t off = ((size_t)(kk * 12 + wv * 3 + n) * 64 + l) * 8;
                wr[n] = *(const bf16x8*)(pW1r + off);
                wi[n] = *(const bf16x8*)(pW1i + off);
            }
#pragma unroll
            for (int m = 0; m < 2; ++m)
#pragma unroll
                for (int n = 0; n < 3; ++n) {
                    aR[m][n] = __builtin_amdgcn_mfma_f32_16x16x32_bf16(ar[m],  wr[n], aR[m][n], 0, 0, 0);
                    aR[m][n] = __builtin_amdgcn_mfma_f32_16x16x32_bf16(ain[m], wi[n], aR[m][n], 0, 0, 0);
                    aI[m][n] = __builtin_amdgcn_mfma_f32_16x16x32_bf16(ar[m],  wi[n], aI[m][n], 0, 0, 0);
                    aI[m][n] = __builtin_amdgcn_mfma_f32_16x16x32_bf16(ai[m],  wr[n], aI[m][n], 0, 0, 0);
                }
        }
        __syncthreads();   // all P2 A-reads of Y done before R2/R3... (R2/R3 are
                           // fresh regions; barrier here orders Y-reads vs P3's
                           // later overwrite of R0/R1 and publishes r1/i1 below)
#pragma unroll
        for (int m = 0; m < 2; ++m)
#pragma unroll
            for (int n = 0; n < 3; ++n)
#pragma unroll
                for (int r = 0; r < 4; ++r) {
                    float rv = aR[m][n][r]; rv = rv > 0.f ? rv : 0.f;
                    float iv = aI[m][n][r]; iv = iv > 0.f ? iv : 0.f;
                    const int pos = (wv * 3 + n) * 528 + (m * 16 + lg * 4 + r) * 16 + lc;
                    lds[2][pos] = f2bf(rv);
                    lds[3][pos] = f2bf(iv);
                }
    }
    __syncthreads();

    // ================= P3: r2 = r1 W2r - i1 W2i + b2r =================
    {
        f32x4 cR[2][3];
#pragma unroll
        for (int n = 0; n < 3; ++n) {
            const float br = b2[(size_t)(0 * 4 + blk) * BLK + col0 + n * 16 + lc];
#pragma unroll
            for (int m = 0; m < 2; ++m) cR[m][n] = (f32x4){br, br, br, br};
        }
#pragma unroll
        for (int kk = 0; kk < 6; ++kk) {
            const int csubA = 2 * kk + (lg >> 1);
            const int apos  = csubA * 528 + lc * 16 + (lg & 1) * 8;
            bf16x8 ar[2], ain[2];
#pragma unroll
            for (int m = 0; m < 2; ++m) {
                ar[m]  = *(const bf16x8*)&lds[2][apos + m * 256];
                ain[m] = neg8(*(const bf16x8*)&lds[3][apos + m * 256]);
            }
            bf16x8 wr[3], wi[3];
#pragma unroll
            for (int n = 0; n < 3; ++n) {
                const size_t off = ((size_t)(kk * 12 + wv * 3 + n) * 64 + l) * 8;
                wr[n] = *(const bf16x8*)(pW2r + off);
                wi[n] = *(const bf16x8*)(pW2i + off);
            }
#pragma unroll
            for (int m = 0; m < 2; ++m)
#pragma unroll
                for (int n = 0; n < 3; ++n) {
                    cR[m][n] = __builtin_amdgcn_mfma_f32_16x16x32_bf16(ar[m],  wr[n], cR[m][n], 0, 0, 0);
                    cR[m][n] = __builtin_amdgcn_mfma_f32_16x16x32_bf16(ain[m], wi[n], cR[m][n], 0, 0, 0);
                }
        }
        // r2 subtile -> R0 (Y dead), r2_t interleaved -> R1 (Y dead)
#pragma unroll
        for (int m = 0; m < 2; ++m)
#pragma unroll
            for (int n = 0; n < 3; ++n) {
                const int csub = wv * 3 + n;
#pragma unroll
                for (int rp = 0; rp < 2; ++rp) {
                    const ushort lo = f2bf(cR[m][n][2 * rp]);
                    const ushort hi = f2bf(cR[m][n][2 * rp + 1]);
                    const int kh0 = m * 16 + lg * 4 + 2 * rp;
                    lds[0][csub * 528 + kh0 * 16 + lc]       = lo;
                    lds[0][csub * 528 + (kh0 + 1) * 16 + lc] = hi;
                    const int hp = kh0 >> 1;
                    const int post = csub * 528 + hp * 32 + ((lc ^ ((hp & 7) << 1)) << 1);
                    *(uint*)&lds[1][post] = (uint)lo | ((uint)hi << 16);
                }
            }
    }
    __syncthreads();

    // ================= P4: i2 = r2 W2i + i1 W2r + b2i =================
    f32x4 cI[2][3];
    {
#pragma unroll
        for (int n = 0; n < 3; ++n) {
            const float bi = b2[(size_t)(1 * 4 + blk) * BLK + col0 + n * 16 + lc];
#pragma unroll
            for (int m = 0; m < 2; ++m) cI[m][n] = (f32x4){bi, bi, bi, bi};
        }
#pragma unroll
        for (int kk = 0; kk < 6; ++kk) {
            const int csubA = 2 * kk + (lg >> 1);
            const int apos  = csubA * 528 + lc * 16 + (lg & 1) * 8;
            bf16x8 a2[2], i1[2];
#pragma unroll
            for (int m = 0; m < 2; ++m) {
                a2[m] = *(const bf16x8*)&lds[0][apos + m * 256];   // r2
                i1[m] = *(const bf16x8*)&lds[3][apos + m * 256];   // i1
            }
            bf16x8 wr[3], wi[3];
#pragma unroll
            for (int n = 0; n < 3; ++n) {
                const size_t off = ((size_t)(kk * 12 + wv * 3 + n) * 64 + l) * 8;
                wr[n] = *(const bf16x8*)(pW2r + off);
                wi[n] = *(const bf16x8*)(pW2i + off);
            }
#pragma unroll
            for (int m = 0; m < 2; ++m)
#pragma unroll
                for (int n = 0; n < 3; ++n) {
                    cI[m][n] = __builtin_amdgcn_mfma_f32_16x16x32_bf16(a2[m], wi[n], cI[m][n], 0, 0, 0);
                    cI[m][n] = __builtin_amdgcn_mfma_f32_16x16x32_bf16(i1[m], wr[n], cI[m][n], 0, 0, 0);
                }
        }
        // i2_t interleaved -> R2 (r1 dead). Own stripe: consumed by this wave only.
#pragma unroll
        for (int m = 0; m < 2; ++m)
#pragma unroll
            for (int n = 0; n < 3; ++n) {
                const int csub = wv * 3 + n;
#pragma unroll
                for (int rp = 0; rp < 2; ++rp) {
                    const int hp = (m * 16 + lg * 4 + 2 * rp) >> 1;
                    const int post = csub * 528 + hp * 32 + ((lc ^ ((hp & 7) << 1)) << 1);
                    *(uint*)&lds[2][post] =
                        (uint)f2bf(cI[m][n][2 * rp]) | ((uint)f2bf(cI[m][n][2 * rp + 1]) << 16);
                }
            }
    }
    // no barrier: P5 reads only this wave's stripes (r2_t written pre-barrier,
    // i2_t written by this wave)

    // ================= P5: inverse H-FFT + store =================
    {
        bf16x8 ci[2], si[2], sin_[2];
#pragma unroll
        for (int m = 0; m < 2; ++m) {
            ci[m]   = *(const bf16x8*)(TW + ((size_t)(2 * 2 + m) * 64 + l) * 8);
            si[m]   = *(const bf16x8*)(TW + ((size_t)(3 * 2 + m) * 64 + l) * 8);
            sin_[m] = neg8(si[m]);
        }
        bf16x8 r2b[3], i2b[3];
#pragma unroll
        for (int n = 0; n < 3; ++n) {
            const int csub = wv * 3 + n;
            union { bf16x8 v; uint d[4]; } ur, ui;
#pragma unroll
            for (int t = 0; t < 4; ++t) {
                const int hp = lg * 4 + t;
                const int pos = csub * 528 + hp * 32 + ((lc ^ ((hp & 7) << 1)) << 1);
                ur.d[t] = *(const uint*)&lds[1][pos];
                ui.d[t] = *(const uint*)&lds[2][pos];
            }
            r2b[n] = ur.v; i2b[n] = ui.v;
        }
        f32x4 zr[2][3] = {}, zi[2][3] = {};
#pragma unroll
        for (int m = 0; m < 2; ++m)
#pragma unroll
            for (int n = 0; n < 3; ++n) {
                zr[m][n] = __builtin_amdgcn_mfma_f32_16x16x32_bf16(ci[m],   r2b[n], zr[m][n], 0, 0, 0);
                zr[m][n] = __builtin_amdgcn_mfma_f32_16x16x32_bf16(sin_[m], i2b[n], zr[m][n], 0, 0, 0);
                zi[m][n] = __builtin_amdgcn_mfma_f32_16x16x32_bf16(ci[m],   i2b[n], zi[m][n], 0, 0, 0);
                zi[m][n] = __builtin_amdgcn_mfma_f32_16x16x32_bf16(si[m],   r2b[n], zi[m][n], 0, 0, 0);
            }
        // store back to spectrum (same swizzled layout, in place, u32 pairs)
#pragma unroll
        for (int m = 0; m < 2; ++m)
#pragma unroll
            for (int n = 0; n < 3; ++n) {
                const size_t cbase = gR + (size_t)(wv * 3 + n) * 512;
#pragma unroll
                for (int rp = 0; rp < 2; ++rp) {
                    const int hp = (m * 16 + lg * 4 + 2 * rp) >> 1;
                    const size_t pos = cbase + hp * 32 + ((lc ^ ((hp & 7) << 1)) << 1);
                    *(uint*)(spec + pos) =
                        (uint)f2bf(zr[m][n][2 * rp]) | ((uint)f2bf(zr[m][n][2 * rp + 1]) << 16);
                    *(uint*)(spec + pos + PLANE_U) =
                        (uint)f2bf(zi[m][n][2 * rp]) | ((uint)f2bf(zi[m][n][2 * rp + 1]) << 16);
                }
            }
    }
}

// ---------------------------------------------------------------------------
// k3: inverse real FFT along W. WG = (b, h-pair, c-chunk); u32 pair loads.
// ---------------------------------------------------------------------------
__global__ __launch_bounds__(256) void k_irfft_w(const ushort* __restrict__ spec,
                                                 float* __restrict__ out) {
    const int bid = blockIdx.x;
    const int cc = bid % 3;
    const int hp = (bid / 3) & 15;
    const int b  = bid / 48;
    const int c  = cc * 256 + threadIdx.x;

    const size_t base = (size_t)b * (WF * 2 * PLANE_U)
                      + (size_t)(c >> 4) * 512 + hp * 32
                      + (((c & 15) ^ ((hp & 7) << 1)) << 1);
    float xr0[17], xi0[17], xr1[17], xi1[17];
#pragma unroll
    for (int k = 0; k <= 16; ++k) {
        const uint ur = *(const uint*)(spec + base + (size_t)k * (2 * PLANE_U));
        const uint ui = *(const uint*)(spec + base + (size_t)k * (2 * PLANE_U) + PLANE_U);
        xr0[k] = bf2f((ushort)ur); xr1[k] = bf2f((ushort)(ur >> 16));
        xi0[k] = bf2f((ushort)ui); xi1[k] = bf2f((ushort)(ui >> 16));
    }
    float* po0 = out + ((size_t)b * 1024 + hp * 64) * CC + c;
    float* po1 = po0 + (size_t)32 * CC;
#pragma unroll
    for (int w = 0; w <= 16; ++w) {
        float e0 = xr0[0] + ((w & 1) ? -xr0[16] : xr0[16]);
        float e1 = xr1[0] + ((w & 1) ? -xr1[16] : xr1[16]);
        float o0 = 0.f, o1 = 0.f;
#pragma unroll
        for (int k = 1; k <= 15; ++k) {
            const int t = (k * w) & 31;
            e0 = fmaf(2.f * xr0[k],  C32[t], e0);
            o0 = fmaf(2.f * xi0[k], -S32[t], o0);
            e1 = fmaf(2.f * xr1[k],  C32[t], e1);
            o1 = fmaf(2.f * xi1[k], -S32[t], o1);
        }
        po0[(size_t)w * CC] = (e0 + o0) * 0.03125f;
        po1[(size_t)w * CC] = (e1 + o1) * 0.03125f;
        if (w >= 1 && w <= 15) {
            po0[(size_t)(32 - w) * CC] = (e0 - o0) * 0.03125f;
            po1[(size_t)(32 - w) * CC] = (e1 - o1) * 0.03125f;
        }
    }
}

// ---------------------------------------------------------------------------
extern "C" void kernel_launch(void* const* d_in, const int* in_sizes, int n_in,
                              void* d_out, int out_size, void* d_ws, size_t ws_size,
                              hipStream_t stream) {
    const float* x  = (const float*)d_in[0];
    const float* w1 = (const float*)d_in[1];
    const float* b1 = (const float*)d_in[2];
    const float* w2 = (const float*)d_in[3];
    const float* b2 = (const float*)d_in[4];
    float* out = (float*)d_out;

    ushort* pw   = (ushort*)d_ws;
    ushort* spec = pw + PW_ELEMS;

    k_pack<<<dim3((unsigned)((PW_ELEMS + 255) / 256)), dim3(256), 0, stream>>>(w1, w2, pw);
    k_rfft_w<<<dim3(BATCH * 16 * 3), dim3(256), 0, stream>>>(x, spec);
    k_fft_mix<<<dim3(4 * BATCH * WF), dim3(256), 0, stream>>>(spec, pw, b1, b2);
    k_irfft_w<<<dim3(BATCH * 16 * 3), dim3(256), 0, stream>>>(spec, out);
}